// Round 5
// baseline (209.885 us; speedup 1.0000x reference)
//
#include <hip/hip_runtime.h>

// ROSA 1-bit, B=4, T=2048, C=128 (512 sequences).
// Round 5: systolic i-tiled diagonal DP. Tile k = words [8k, 8k+8). Each
// 8-lane group streams consecutive diagonals through the tile: lane lm owns
// word 8k+lm; at step s it processes diagonal d = D0 + s - lm; the run hands
// off via one __shfl_up per step (replaces round-3/4's ballot + segmented
// scan + divergent inc0 loop). Boundary seed = 1-word branchless backscan
// (exact rare fallback). __launch_bounds__(256,2) gives VGPR headroom so
// lmax[32] stays in arch VGPRs (round-4 VGPR_Count=36 => AGPR shuttling).

#define TT 2048
#define CC 128
#define NW 64
#define NSEQ 512
#define SBITS_WORDS (NSEQ * NW)       // 128 KB
#define RES_WORDS (NSEQ * TT)         // 4 MB, layout [q][i]

// ---------------- kernel 0: pack bits ----------------
__global__ void k_bits(const float* __restrict__ x, unsigned* __restrict__ sbits)
{
    const int b = blockIdx.x >> 6;
    const int w = blockIdx.x & 63;
    const int t = threadIdx.x;
    __shared__ unsigned char sbyt[32 * 132];

    #pragma unroll
    for (int r = 0; r < 16; ++r) {
        const int e  = t + (r << 8);
        const int ii = e >> 7;
        const int c  = e & 127;
        const float v = x[((size_t)(b * TT + (w << 5) + ii)) * CC + c];
        sbyt[ii * 132 + c] = (v > 0.0f) ? 1u : 0u;
    }
    __syncthreads();

    if (t < CC) {
        unsigned word = 0u;
        #pragma unroll
        for (int ii = 0; ii < 32; ++ii)
            word |= (unsigned)(sbyt[ii * 132 + t] & 1u) << ii;
        sbits[((b << 7) | t) * NW + w] = word;
    }
}

// ---------------- kernel 1: systolic tiled diagonal DP ----------------
// grid (4096): bx -> k = 7 - (bx>>9) (big tiles first), q = bx & 511.
// Block: 256 thr = 4 waves = 32 streams; stream st covers diagonals
// [1 + st*L, 1 + (st+1)*L), L = 8k+8 (all admissible d <= 256k+255).
__global__ __launch_bounds__(256, 2) void k_dp3(
    const unsigned* __restrict__ sbits, unsigned* __restrict__ res)
{
    const int bx = blockIdx.x;
    const int k  = 7 - (bx >> 9);
    const int q  = bx & 511;
    const int L  = (k << 3) + 8;
    const int nsteps = L + 7;

    const int tid  = threadIdx.x;
    const int lane = tid & 63;
    const int wv   = tid >> 6;
    const int g    = lane >> 3;
    const int lm   = lane & 7;
    const int st   = (wv << 3) | g;
    const int wB   = k << 3;
    const int wloc = wB + lm;
    const int dbase = 1 + st * L - lm;     // d = dbase + s

    __shared__ unsigned pad[136];          // [0..63]=0, [64+w]=W[w], [128..]=0
    __shared__ unsigned wres[4][8][33];

    if (tid < 64) pad[tid] = 0u;
    else if (tid < 128) pad[tid] = sbits[q * NW + (tid - 64)];
    else if (tid < 136) pad[tid] = 0u;
    __syncthreads();

    const unsigned a  = pad[64 + wloc];
    const unsigned W1 = (k > 0) ? pad[64 + wB - 1] : 0u;

    unsigned lmax[32];
    #pragma unroll
    for (int bb = 0; bb < 32; ++bb) lmax[bb] = 0u;

    unsigned run_prev = 0u;

    for (int s = 0; s < nsteps; ++s) {
        const int d  = dbase + s;
        const int dw = d >> 5;                       // arith shift (d may be <1)
        const int dr = d & 31;
        const unsigned dcode = (unsigned)(TT - d) & 2047u;  // harmless when d OOR

        const int si = wloc - dw;
        const unsigned b0 = pad[64 + si];
        const unsigned b1 = pad[63 + si];
        const unsigned sh = dr ? ((b0 << dr) | (b1 >> (32 - dr))) : b0;
        unsigned em = (si > 0) ? 0xFFFFFFFFu : ((si == 0) ? (0xFFFFFFFFu << dr) : 0u);
        if (d < 1) em = 0u;
        const unsigned m = (~(a ^ sh)) & em;

        // systolic hand-off: run for my diagonal from the lane below
        const unsigned rin = (unsigned)__shfl_up((int)run_prev, 1, 64);

        // boundary seed for group-head lanes (word wB): 1-word branchless scan
        unsigned inc0 = 0u;
        if (k > 0) {
            const int s1 = (wB - 1) - dw;
            const unsigned c0 = pad[64 + s1];
            const unsigned c1 = pad[63 + s1];
            const unsigned sh1 = dr ? ((c0 << dr) | (c1 >> (32 - dr))) : c0;
            const unsigned e1 = (s1 > 0) ? 0xFFFFFFFFu
                              : ((s1 == 0) ? (0xFFFFFFFFu << dr) : 0u);
            const unsigned m1 = (~(W1 ^ sh1)) & e1;
            const unsigned t1 = (m1 == 0xFFFFFFFFu) ? 32u : (unsigned)__builtin_clz(~m1);
            inc0 = t1;
            // exact rare fallback (P ~ 2^-32 per sample): scan further back
            if (__builtin_expect(
                    __ballot((lm == 0) && (t1 == 32u)) != 0ULL, 0)) {
                if ((lm == 0) && t1 == 32u) {
                    for (int w = wB - 2; w >= 0; --w) {
                        const int sw = w - dw;
                        const unsigned u0 = pad[64 + sw];
                        const unsigned u1 = pad[63 + sw];
                        const unsigned shw = dr ? ((u0 << dr) | (u1 >> (32 - dr))) : u0;
                        const unsigned ew = (sw > 0) ? 0xFFFFFFFFu
                                          : ((sw == 0) ? (0xFFFFFFFFu << dr) : 0u);
                        const unsigned mw = (~(pad[64 + w] ^ shw)) & ew;
                        const unsigned tw = (mw == 0xFFFFFFFFu) ? 32u
                                          : (unsigned)__builtin_clz(~mw);
                        inc0 += tw;
                        if (tw < 32u) break;
                    }
                }
            }
        }

        const unsigned run_in = (lm == 0) ? inc0 : rin;
        unsigned pkv = (run_in << 11) | dcode;

        #pragma unroll
        for (int bb = 0; bb < 32; ++bb) {
            unsigned keep;
            asm("v_bfe_i32 %0, %3, %4, 1\n\t"
                "v_add_u32 %1, 0x800, %1\n\t"
                "v_bfi_b32 %1, %0, %1, %5\n\t"
                "v_max_u32 %2, %2, %1"
                : "=&v"(keep), "+v"(pkv), "+v"(lmax[bb])
                : "v"(m), "n"(bb), "v"(dcode));
        }
        run_prev = pkv >> 11;
    }

    // --- merge 32 streams sharing each word ---
    #pragma unroll
    for (int bb = 0; bb < 32; ++bb) {
        unsigned v = lmax[bb];
        v = max(v, (unsigned)__shfl_xor((int)v, 8, 64));
        v = max(v, (unsigned)__shfl_xor((int)v, 16, 64));
        v = max(v, (unsigned)__shfl_xor((int)v, 32, 64));
        lmax[bb] = v;
    }
    if (lane < 8) {
        #pragma unroll
        for (int bb = 0; bb < 32; ++bb) wres[wv][lane][bb] = lmax[bb];
    }
    __syncthreads();

    {
        const int lw = tid >> 5, bb = tid & 31;
        const unsigned v = max(max(wres[0][lw][bb], wres[1][lw][bb]),
                               max(wres[2][lw][bb], wres[3][lw][bb]));
        if (v >> 11) {
            const int i = ((wB + lw) << 5) + bb;
            atomicMax(&res[(size_t)q * TT + i], v);
        }
    }
}

// ---------------- kernel 2: decode (LDS transpose) ----------------
__global__ void k_dec(const unsigned* __restrict__ sbits,
                      const unsigned* __restrict__ res,
                      const float* __restrict__ emb0,
                      const float* __restrict__ emb1,
                      float* __restrict__ out)
{
    const int b  = blockIdx.y;
    const int i0 = blockIdx.x << 4;
    const int t  = threadIdx.x;
    __shared__ float trans[16][CC + 4];

    const int c  = t >> 1;
    const int q8 = (t & 1) << 3;
    const unsigned* rp = res + ((size_t)((b << 7) | c) * TT) + i0 + q8;
    const unsigned* bw = sbits + ((size_t)((b << 7) | c)) * NW;
    const float e0 = emb0[c], e1 = emb1[c];

    #pragma unroll
    for (int jj = 0; jj < 8; ++jj) {
        const unsigned v = rp[jj];
        const int i = i0 + q8 + jj;
        float val = 0.0f;
        if (v >> 11) {
            const int d   = TT - (int)(v & 2047u);
            const int e1p = i - d + 1;
            val = ((bw[e1p >> 5] >> (e1p & 31)) & 1u) ? e1 : e0;
        }
        trans[q8 + jj][c] = val;
    }
    __syncthreads();

    const int ii = t >> 4;
    const int c0 = (t & 15) << 3;
    float4 w0 = *(const float4*)&trans[ii][c0];
    float4 w1 = *(const float4*)&trans[ii][c0 + 4];
    float* op = out + ((size_t)(b * TT + i0 + ii)) * CC + c0;
    *(float4*)op       = w0;
    *(float4*)(op + 4) = w1;
}

extern "C" void kernel_launch(void* const* d_in, const int* in_sizes, int n_in,
                              void* d_out, int out_size, void* d_ws, size_t ws_size,
                              hipStream_t stream)
{
    const float* x    = (const float*)d_in[0];
    const float* emb0 = (const float*)d_in[1];
    const float* emb1 = (const float*)d_in[2];
    float* out        = (float*)d_out;

    unsigned* sbits = (unsigned*)d_ws;                    // 128 KB
    unsigned* res   = (unsigned*)d_ws + SBITS_WORDS;      // 4 MB

    hipMemsetAsync((void*)res, 0, (size_t)RES_WORDS * 4, stream);
    k_bits<<<dim3(4 * 64), dim3(256), 0, stream>>>(x, sbits);
    k_dp3<<<dim3(4096), dim3(256), 0, stream>>>(sbits, res);
    k_dec<<<dim3(TT / 16, 4), dim3(256), 0, stream>>>(sbits, res, emb0, emb1, out);
}

// Round 6
// 179.572 us; speedup vs baseline: 1.1688x; 1.1688x over previous
//
#include <hip/hip_runtime.h>

// ROSA 1-bit, B=4, T=2048, C=128 (512 sequences).
// Round 6: round-4 geometry (proven absmax 0, 590k wave-steps) with the two
// per-step overhead blocks removed:
//  (a) per-diagonal boundary seeds PRECOMPUTED once per block (LDS seedl[256])
//      -> in-loop seed = 1 LDS broadcast + cndmask (was ~18 inst divergent scan);
//  (b) incoming-run via 3-inst clz fast path + exact rare fallback
//      (ballot-gated backscan, P~2^-32) (was ~25-inst segmented scan every step).
// Quad (4 VALU/bit asm), merge, k_bits, k_dec unchanged.

#define TT 2048
#define CC 128
#define NW 64
#define NSEQ 512
#define SBITS_WORDS (NSEQ * NW)       // 128 KB
#define RES_WORDS (NSEQ * TT)         // 4 MB, layout [q][i]

// ---------------- kernel 0: pack bits ----------------
__global__ void k_bits(const float* __restrict__ x, unsigned* __restrict__ sbits)
{
    const int b = blockIdx.x >> 6;
    const int w = blockIdx.x & 63;
    const int t = threadIdx.x;
    __shared__ unsigned char sbyt[32 * 132];

    #pragma unroll
    for (int r = 0; r < 16; ++r) {
        const int e  = t + (r << 8);
        const int ii = e >> 7;
        const int c  = e & 127;
        const float v = x[((size_t)(b * TT + (w << 5) + ii)) * CC + c];
        sbyt[ii * 132 + c] = (v > 0.0f) ? 1u : 0u;
    }
    __syncthreads();

    if (t < CC) {
        unsigned word = 0u;
        #pragma unroll
        for (int ii = 0; ii < 32; ++ii)
            word |= (unsigned)(sbyt[ii * 132 + t] & 1u) << ii;
        sbits[((b << 7) | t) * NW + w] = word;
    }
}

// ---------------- kernel 1: tiled diagonal DP ----------------
__global__ __launch_bounds__(256, 4) void k_dp2(
    const unsigned* __restrict__ sbits, unsigned* __restrict__ res)
{
    const int u = blockIdx.x;            // 0..35 (triangular (k, chunk))
    const int q = blockIdx.y;            // sequence = b*128 + c
    int k = 0;
    #pragma unroll
    for (int kk = 1; kk < 8; ++kk) if (u >= (kk * (kk + 1)) / 2) k = kk;
    const int chunk = u - (k * (k + 1)) / 2;
    const int D0 = 1 + (chunk << 8);

    const int tid  = threadIdx.x;
    const int lane = tid & 63;
    const int wv   = tid >> 6;
    const int g    = lane >> 3;          // stream in wave
    const int lm   = lane & 7;           // lane within stream
    const int wB   = k << 3;
    const int wloc = wB + lm;            // fixed output word of this lane
    const int kb   = k << 8;

    __shared__ unsigned pad[128];        // [0..63]=0, [64+w]=word w
    __shared__ unsigned seedl[256];      // incoming run at tile base per diagonal
    __shared__ unsigned wres[4][8][33];

    if (tid < 64) pad[tid] = 0u;
    else if (tid < 128) pad[tid] = sbits[q * NW + (tid - 64)];
    __syncthreads();

    // --- seed precompute: thread t -> diagonal D0+t ---
    {
        const int d = D0 + tid;
        unsigned acc = 0u;
        if (d < kb) {
            const int dw = d >> 5, dr = d & 31;
            for (int w = wB - 1; w >= 0; --w) {
                const int sw = w - dw;
                const unsigned u0 = pad[64 + sw];
                const unsigned u1 = pad[63 + sw];
                const unsigned shw = dr ? ((u0 << dr) | (u1 >> (32 - dr))) : u0;
                const unsigned ew = (sw > 0) ? 0xFFFFFFFFu
                                  : ((sw == 0) ? (0xFFFFFFFFu << dr) : 0u);
                const unsigned mw = (~(pad[64 + w] ^ shw)) & ew;
                const unsigned t2 = (mw == 0xFFFFFFFFu) ? 32u
                                  : (unsigned)__builtin_clz(~mw);
                acc += t2;
                if (t2 < 32u) break;
            }
        }
        seedl[tid] = acc;
    }
    __syncthreads();

    const unsigned a = pad[64 + wloc];

    unsigned lmax[32];
    #pragma unroll
    for (int bb = 0; bb < 32; ++bb) lmax[bb] = 0u;

    #pragma unroll
    for (int it = 0; it < 8; ++it) {
        const int d  = D0 + (it << 5) + (wv << 3) + g;
        const int dw = d >> 5;
        const int dr = d & 31;
        const unsigned dcode = (unsigned)(TT - d);   // 0 at d==2048 (em=0 then)

        const int s = wloc - dw;
        const unsigned b0 = pad[64 + s];
        const unsigned b1 = pad[63 + s];
        const unsigned sh = dr ? ((b0 << dr) | (b1 >> (32 - dr))) : b0;
        const unsigned em = (s > 0) ? 0xFFFFFFFFu
                          : ((s == 0) ? (0xFFFFFFFFu << dr) : 0u);
        const unsigned m = (~(a ^ sh)) & em;

        // --- incoming run: seed for stream heads, clz fast path otherwise ---
        const unsigned seedv = seedl[(it << 5) + (wv << 3) + g];
        const unsigned pm = (unsigned)__shfl_up((int)m, 1, 64);
        const unsigned lead = (unsigned)__builtin_clz(~pm | 1u);
        unsigned inc = (lm == 0) ? seedv : lead;

        // exact rare fallback: some lane's previous word fully matched
        if (__builtin_expect(
                __ballot((lm > 0) && (pm == 0xFFFFFFFFu)) != 0ULL, 0)) {
            if ((lm > 0) && (pm == 0xFFFFFFFFu)) {
                unsigned acc = 0u;
                int w;
                for (w = wloc - 1; w >= wB; --w) {
                    const int sw = w - dw;
                    const unsigned u0 = pad[64 + sw];
                    const unsigned u1 = pad[63 + sw];
                    const unsigned shw = dr ? ((u0 << dr) | (u1 >> (32 - dr))) : u0;
                    const unsigned ew = (sw > 0) ? 0xFFFFFFFFu
                                      : ((sw == 0) ? (0xFFFFFFFFu << dr) : 0u);
                    const unsigned mw = (~(pad[64 + w] ^ shw)) & ew;
                    const unsigned t2 = (mw == 0xFFFFFFFFu) ? 32u
                                      : (unsigned)__builtin_clz(~mw);
                    acc += t2;
                    if (t2 < 32u) break;
                }
                if (w < wB) acc += seedv;
                inc = acc;
            }
        }

        // --- per-bit run + packed max: 4 VALU/bit ---
        unsigned pkv = (inc << 11) | dcode;
        #pragma unroll
        for (int bb = 0; bb < 32; ++bb) {
            unsigned keep;
            asm("v_bfe_i32 %0, %3, %4, 1\n\t"
                "v_add_u32 %1, 0x800, %1\n\t"
                "v_bfi_b32 %1, %0, %1, %5\n\t"
                "v_max_u32 %2, %2, %1"
                : "=&v"(keep), "+v"(pkv), "+v"(lmax[bb])
                : "v"(m), "n"(bb), "v"(dcode));
        }
    }

    // --- reduce the 8 streams sharing each word ---
    #pragma unroll
    for (int bb = 0; bb < 32; ++bb) {
        unsigned v = lmax[bb];
        v = max(v, (unsigned)__shfl_xor((int)v, 8, 64));
        v = max(v, (unsigned)__shfl_xor((int)v, 16, 64));
        v = max(v, (unsigned)__shfl_xor((int)v, 32, 64));
        lmax[bb] = v;
    }
    if (lane < 8) {
        #pragma unroll
        for (int bb = 0; bb < 32; ++bb) wres[wv][lane][bb] = lmax[bb];
    }
    __syncthreads();

    // --- block merge + contiguous atomics into res[q][i] ---
    {
        const int lw = tid >> 5, bb = tid & 31;
        const unsigned v = max(max(wres[0][lw][bb], wres[1][lw][bb]),
                               max(wres[2][lw][bb], wres[3][lw][bb]));
        if (v >> 11) {
            const int i = ((wB + lw) << 5) + bb;
            atomicMax(&res[(size_t)q * TT + i], v);
        }
    }
}

// ---------------- kernel 2: decode (LDS transpose) ----------------
__global__ void k_dec(const unsigned* __restrict__ sbits,
                      const unsigned* __restrict__ res,
                      const float* __restrict__ emb0,
                      const float* __restrict__ emb1,
                      float* __restrict__ out)
{
    const int b  = blockIdx.y;
    const int i0 = blockIdx.x << 4;
    const int t  = threadIdx.x;
    __shared__ float trans[16][CC + 4];

    const int c  = t >> 1;
    const int q8 = (t & 1) << 3;
    const unsigned* rp = res + ((size_t)((b << 7) | c) * TT) + i0 + q8;
    const unsigned* bw = sbits + ((size_t)((b << 7) | c)) * NW;
    const float e0 = emb0[c], e1 = emb1[c];

    #pragma unroll
    for (int jj = 0; jj < 8; ++jj) {
        const unsigned v = rp[jj];
        const int i = i0 + q8 + jj;
        float val = 0.0f;
        if (v >> 11) {
            const int d   = TT - (int)(v & 2047u);
            const int e1p = i - d + 1;
            val = ((bw[e1p >> 5] >> (e1p & 31)) & 1u) ? e1 : e0;
        }
        trans[q8 + jj][c] = val;
    }
    __syncthreads();

    const int ii = t >> 4;
    const int c0 = (t & 15) << 3;
    float4 w0 = *(const float4*)&trans[ii][c0];
    float4 w1 = *(const float4*)&trans[ii][c0 + 4];
    float* op = out + ((size_t)(b * TT + i0 + ii)) * CC + c0;
    *(float4*)op       = w0;
    *(float4*)(op + 4) = w1;
}

extern "C" void kernel_launch(void* const* d_in, const int* in_sizes, int n_in,
                              void* d_out, int out_size, void* d_ws, size_t ws_size,
                              hipStream_t stream)
{
    const float* x    = (const float*)d_in[0];
    const float* emb0 = (const float*)d_in[1];
    const float* emb1 = (const float*)d_in[2];
    float* out        = (float*)d_out;

    unsigned* sbits = (unsigned*)d_ws;                    // 128 KB
    unsigned* res   = (unsigned*)d_ws + SBITS_WORDS;      // 4 MB

    hipMemsetAsync((void*)res, 0, (size_t)RES_WORDS * 4, stream);
    k_bits<<<dim3(4 * 64), dim3(256), 0, stream>>>(x, sbits);
    k_dp2<<<dim3(36, NSEQ), dim3(256), 0, stream>>>(sbits, res);
    k_dec<<<dim3(TT / 16, 4), dim3(256), 0, stream>>>(sbits, res, emb0, emb1, out);
}